// Round 14
// baseline (358.416 us; speedup 1.0000x reference)
//
#include <hip/hip_runtime.h>
#include <hip/hip_cooperative_groups.h>

namespace cg = cooperative_groups;

#define DN 64
#define DE 32
#define DO 64
#define NB 256    // scan phase-1 chunk blocks (requires n_nodes <= NB*256)
#define TP 128    // CSR positions per agg block (2 waves x 64)
#define CH 8      // Ps prefetch chunk
#define COOPB 1024

typedef __attribute__((ext_vector_type(8))) short bf16x8;
typedef __attribute__((ext_vector_type(4))) float f32x4;

__device__ inline unsigned pack_bf16(float a, float b) {
    unsigned ua = __float_as_uint(a), ub = __float_as_uint(b);
    ua = (ua + 0x7fffu + ((ua >> 16) & 1u)) >> 16;     // RNE bf16
    ub = (ub + 0x7fffu + ((ub >> 16) & 1u)) >> 16;
    return ua | (ub << 16);
}
__device__ inline unsigned short bf16_1(float a) {
    unsigned u = __float_as_uint(a);
    return (unsigned short)((u + 0x7fffu + ((u >> 16) & 1u)) >> 16);
}
__device__ inline float bf16f(unsigned short v) {
    return __uint_as_float((unsigned)v << 16);
}

union bfu { unsigned u[4]; bf16x8 v; };

// ---------------------------------------------------------------------------
// K1: MFMA per-node projections (bf16 tables) + degree histogram WITH RANK.
// rank[e] = this edge's index within its dst bucket (atomic return value) --
// lets the scatter phase run atomic-free.
// ---------------------------------------------------------------------------
__global__ void __launch_bounds__(256) pre_hist_kernel(
    const float* __restrict__ node, const float* __restrict__ W_e,
    const int* __restrict__ dst,
    unsigned short* __restrict__ PsB, unsigned short* __restrict__ PdB,
    int* __restrict__ cnt, int* __restrict__ rank_,
    int n_nodes, int n_edges)
{
    const int t    = threadIdx.x;
    const int lane = t & 63;
    const int w    = __builtin_amdgcn_readfirstlane((int)(t >> 6));
    const int l15  = lane & 15;
    const int k0   = (lane >> 4) << 3;

    bfu bS[4][2], bD[4][2];
#pragma unroll
    for (int Nt = 0; Nt < 4; ++Nt) {
        const int col = (Nt << 4) | l15;
#pragma unroll
        for (int ks = 0; ks < 2; ++ks) {
            float ws[8], wd[8];
#pragma unroll
            for (int e = 0; e < 8; ++e) {
                ws[e] = W_e[(ks * 32 + k0 + e) * DO + col];
                wd[e] = W_e[(96 + ks * 32 + k0 + e) * DO + col];
            }
#pragma unroll
            for (int q = 0; q < 4; ++q) {
                bS[Nt][ks].u[q] = pack_bf16(ws[2 * q], ws[2 * q + 1]);
                bD[Nt][ks].u[q] = pack_bf16(wd[2 * q], wd[2 * q + 1]);
            }
        }
    }

    const int row0 = blockIdx.x * 64 + w * 16;
    if (row0 < n_nodes) {
        bfu aF[2];
#pragma unroll
        for (int ks = 0; ks < 2; ++ks) {
            const int r = min(row0 + l15, n_nodes - 1);
            const float* __restrict__ p = node + (size_t)r * DN + ks * 32 + k0;
            const float4 f0 = *(const float4*)p;
            const float4 f1 = *(const float4*)(p + 4);
            aF[ks].u[0] = pack_bf16(f0.x, f0.y);
            aF[ks].u[1] = pack_bf16(f0.z, f0.w);
            aF[ks].u[2] = pack_bf16(f1.x, f1.y);
            aF[ks].u[3] = pack_bf16(f1.z, f1.w);
        }
        const int rb = row0 + ((lane >> 4) << 2);
#pragma unroll
        for (int Nt = 0; Nt < 4; ++Nt) {
            const f32x4 z = {0.f, 0.f, 0.f, 0.f};
            f32x4 aS = __builtin_amdgcn_mfma_f32_16x16x32_bf16(aF[0].v, bS[Nt][0].v, z, 0, 0, 0);
            aS = __builtin_amdgcn_mfma_f32_16x16x32_bf16(aF[1].v, bS[Nt][1].v, aS, 0, 0, 0);
            f32x4 aD = __builtin_amdgcn_mfma_f32_16x16x32_bf16(aF[0].v, bD[Nt][0].v, z, 0, 0, 0);
            aD = __builtin_amdgcn_mfma_f32_16x16x32_bf16(aF[1].v, bD[Nt][1].v, aD, 0, 0, 0);
            const int col = (Nt << 4) | l15;
#pragma unroll
            for (int r = 0; r < 4; ++r) {
                if (rb + r < n_nodes) {
                    PsB[(size_t)(rb + r) * DO + col] = bf16_1(aS[r]);
                    PdB[(size_t)(rb + r) * DO + col] = bf16_1(aD[r]);
                }
            }
        }
    }

    const int gt = blockIdx.x * blockDim.x + t;
    const int nt = gridDim.x * blockDim.x;
    for (int e = gt; e < n_edges; e += nt)
        rank_[e] = atomicAdd(&cnt[dst[e]], 1);
}

// ---------------------------------------------------------------------------
// K2 (cooperative): CSR build = scan_partial | gridsync | scan_final |
// gridsync | atomic-free scatter. Blocks 0..NB-1 do the scans; all COOPB
// blocks participate in scatter. Collapses 3 dispatches + 2 drain
// boundaries into one kernel, keeps cnt/local/bsum L2-hot.
// ---------------------------------------------------------------------------
__global__ void __launch_bounds__(256) csr_coop_kernel(
    const int* __restrict__ dst, const int* __restrict__ src,
    const int* __restrict__ rank_, const int* __restrict__ cnt,
    int* __restrict__ local, int* __restrict__ bsum,
    int* __restrict__ row_start, int2* __restrict__ csr,
    int n_nodes, int n_edges)
{
    cg::grid_group grid = cg::this_grid();
    __shared__ int ws[4], wo[4], blockoff;

    const int t = threadIdx.x, lane = t & 63, w = t >> 6;
    const int C = (n_nodes + NB - 1) / NB;

    // ---- phase A: per-chunk local exclusive scan ----
    if (blockIdx.x < NB) {
        const int i = blockIdx.x * C + t;
        int v = (t < C && i < n_nodes) ? cnt[i] : 0;
        int incl = v;
#pragma unroll
        for (int off = 1; off < 64; off <<= 1) {
            int u = __shfl_up(incl, off, 64);
            if (lane >= off) incl += u;
        }
        if (lane == 63) ws[w] = incl;
        __syncthreads();
        if (t == 0) {
            int r = 0;
#pragma unroll
            for (int q = 0; q < 4; ++q) { wo[q] = r; r += ws[q]; }
            bsum[blockIdx.x] = r;
        }
        __syncthreads();
        if (t < C && i < n_nodes) local[i] = incl - v + wo[w];
    }
    grid.sync();

    // ---- phase B: scan block sums (redundant per block) + emit row_start ----
    if (blockIdx.x < NB) {
        int v = bsum[t];
        int incl = v;
#pragma unroll
        for (int off = 1; off < 64; off <<= 1) {
            int u = __shfl_up(incl, off, 64);
            if (lane >= off) incl += u;
        }
        if (lane == 63) ws[w] = incl;
        __syncthreads();
        if (t == 0) {
            int r = 0;
#pragma unroll
            for (int q = 0; q < 4; ++q) { wo[q] = r; r += ws[q]; }
        }
        __syncthreads();
        const int excl = incl - v + wo[w];
        if (t == (int)blockIdx.x) blockoff = excl;
        if (blockIdx.x == NB - 1 && t == NB - 1) row_start[n_nodes] = excl + v;
        __syncthreads();
        const int i = blockIdx.x * C + t;
        if (t < C && i < n_nodes) row_start[i] = local[i] + blockoff;
    }
    grid.sync();

    // ---- phase C: atomic-free scatter ----
    const int gt = blockIdx.x * blockDim.x + t;
    const int nt = gridDim.x * blockDim.x;
    for (int e = gt; e < n_edges; e += nt) {
        const int d = dst[e];
        const int p = row_start[d] + rank_[e];
        csr[p] = make_int2(e, src[e] | (d << 16));
    }
}

// ---------------------------------------------------------------------------
// K3: MFMA edge-message + segment aggregation (unchanged from R13).
// ---------------------------------------------------------------------------
__global__ void __launch_bounds__(128) agg_mfma_kernel(
    const float* __restrict__ edge,
    const float* __restrict__ W_e, const float* __restrict__ b_e,
    const unsigned short* __restrict__ PsB, const unsigned short* __restrict__ PdB,
    const int* __restrict__ row_start, const int2* __restrict__ csr,
    float* __restrict__ msum, int n_edges)
{
    __shared__ unsigned lds_m[2][32][68];   // 17.4 KB: bf16-paired raw scores

    const int t    = threadIdx.x;
    const int lane = t & 63;
    const int wid  = __builtin_amdgcn_readfirstlane((int)(t >> 6));
    const int wbeg = blockIdx.x * TP + wid * 64;
    const int wcnt = min(n_edges - wbeg, 64);
    if (wcnt <= 0) return;

    const int l15 = lane & 15;
    const int k0  = (lane >> 4) << 3;

    bfu bfr[4];
#pragma unroll
    for (int Nt = 0; Nt < 4; ++Nt) {
        const int col = (Nt << 4) | l15;
        float wv[8];
#pragma unroll
        for (int e = 0; e < 8; ++e)
            wv[e] = W_e[(64 + k0 + e) * DO + col];
#pragma unroll
        for (int v2 = 0; v2 < 4; ++v2)
            bfr[Nt].u[v2] = pack_bf16(wv[2 * v2], wv[2 * v2 + 1]);
    }
    const float bj = b_e[lane];

    const int2 my2 = csr[min(wbeg + lane, n_edges - 1)];

#pragma unroll
    for (int Mt = 0; Mt < 4; ++Mt) {
        const int eA = __shfl(my2.x, (Mt << 4) | l15, 64);
        const float* __restrict__ ep = edge + (size_t)(unsigned)eA * DE + k0;
        const float4 f0 = *(const float4*)(ep);
        const float4 f1 = *(const float4*)(ep + 4);
        bfu afr;
        afr.u[0] = pack_bf16(f0.x, f0.y);
        afr.u[1] = pack_bf16(f0.z, f0.w);
        afr.u[2] = pack_bf16(f1.x, f1.y);
        afr.u[3] = pack_bf16(f1.z, f1.w);
        const int rp0 = (Mt << 3) + ((lane >> 4) << 1);
#pragma unroll
        for (int Nt = 0; Nt < 4; ++Nt) {
            f32x4 dz = {0.f, 0.f, 0.f, 0.f};
            f32x4 d = __builtin_amdgcn_mfma_f32_16x16x32_bf16(afr.v, bfr[Nt].v, dz, 0, 0, 0);
            const int col = (Nt << 4) | l15;
            lds_m[wid][rp0][col]     = pack_bf16(d[0], d[1]);
            lds_m[wid][rp0 + 1][col] = pack_bf16(d[2], d[3]);
        }
    }

    float acc = 0.f, bpd = 0.f;
    int cur_d = -1;

#define FLUSH()                                                         \
    {                                                                   \
        if (row_start[cur_d] >= wbeg)                                   \
            msum[(size_t)cur_d * DO + lane] = acc;                      \
        else                                                            \
            unsafeAtomicAdd(&msum[(size_t)cur_d * DO + lane], acc);     \
    }

#define ISSUE(CHK, BUF)                                                 \
    _Pragma("unroll")                                                   \
    for (int q = 0; q < CH; ++q) {                                      \
        const int y = __builtin_amdgcn_readlane(my2.y, (CHK) * CH + q); \
        BUF[q] = PsB[(size_t)(unsigned)(y & 0xffff) * DO + lane];       \
    }

#define CONSUME(CHK, BUF)                                               \
    {                                                                   \
        unsigned um[4];                                                 \
        _Pragma("unroll")                                               \
        for (int h = 0; h < 4; ++h)                                     \
            um[h] = lds_m[wid][(CHK) * 4 + h][lane];                    \
        _Pragma("unroll")                                               \
        for (int q = 0; q < CH; ++q) {                                  \
            const int y = __builtin_amdgcn_readlane(my2.y, (CHK) * CH + q); \
            const int d = (int)(((unsigned)y) >> 16);                   \
            if (d != cur_d) {                                           \
                if (cur_d >= 0) FLUSH();                                \
                acc = 0.f;                                              \
                cur_d = d;                                              \
                bpd = bj + bf16f(PdB[(size_t)(unsigned)d * DO + lane]); \
            }                                                           \
            const unsigned u = um[q >> 1];                              \
            const float mv = (q & 1) ? __uint_as_float(u & 0xffff0000u) \
                                     : __uint_as_float(u << 16);        \
            acc += fmaxf(mv + bpd + __uint_as_float((unsigned)BUF[q] << 16), 0.f); \
        }                                                               \
    }

    if (wcnt == 64) {
        unsigned short pnA[CH], pnB[CH], pnC[CH];
        ISSUE(0, pnA) ISSUE(1, pnB)
        ISSUE(2, pnC) CONSUME(0, pnA)
        ISSUE(3, pnA) CONSUME(1, pnB)
        ISSUE(4, pnB) CONSUME(2, pnC)
        ISSUE(5, pnC) CONSUME(3, pnA)
        ISSUE(6, pnA) CONSUME(4, pnB)
        ISSUE(7, pnB) CONSUME(5, pnC)
        CONSUME(6, pnA)
        CONSUME(7, pnB)
    } else {
        for (int p = 0; p < wcnt; ++p) {
            const int y = __builtin_amdgcn_readlane(my2.y, p);
            const int s = y & 0xffff;
            const int d = (int)(((unsigned)y) >> 16);
            const float ps = bf16f(PsB[(size_t)(unsigned)s * DO + lane]);
            if (d != cur_d) {
                if (cur_d >= 0) FLUSH();
                acc = 0.f;
                cur_d = d;
                bpd = bj + bf16f(PdB[(size_t)(unsigned)d * DO + lane]);
            }
            const unsigned u = lds_m[wid][p >> 1][lane];
            const float mv = (p & 1) ? __uint_as_float(u & 0xffff0000u)
                                     : __uint_as_float(u << 16);
            acc += fmaxf(mv + bpd + ps, 0.f);
        }
    }

    {   // final flush
        const int sb = row_start[cur_d];
        const int se = row_start[cur_d + 1];
        if (sb >= wbeg && se <= wbeg + wcnt)
            msum[(size_t)cur_d * DO + lane] = acc;
        else
            unsafeAtomicAdd(&msum[(size_t)cur_d * DO + lane], acc);
    }
#undef FLUSH
#undef ISSUE
#undef CONSUME
}

// ---------------------------------------------------------------------------
// K4: MFMA node update: out = relu((msum@Wt)/deg + node@Wb + b_v).
// ---------------------------------------------------------------------------
__global__ void __launch_bounds__(256) node_out_kernel(
    const float* __restrict__ node, const float* __restrict__ msum,
    const int* __restrict__ row_start,
    const float* __restrict__ W_v, const float* __restrict__ b_v,
    float* __restrict__ out, int n_nodes)
{
    const int t    = threadIdx.x;
    const int lane = t & 63;
    const int w    = __builtin_amdgcn_readfirstlane((int)(t >> 6));
    const int l15  = lane & 15;
    const int k0   = (lane >> 4) << 3;

    bfu bT[4][2], bB[4][2];
#pragma unroll
    for (int Nt = 0; Nt < 4; ++Nt) {
        const int col = (Nt << 4) | l15;
#pragma unroll
        for (int ks = 0; ks < 2; ++ks) {
            float wt[8], wb[8];
#pragma unroll
            for (int e = 0; e < 8; ++e) {
                wt[e] = W_v[(ks * 32 + k0 + e) * DO + col];
                wb[e] = W_v[(64 + ks * 32 + k0 + e) * DO + col];
            }
#pragma unroll
            for (int q = 0; q < 4; ++q) {
                bT[Nt][ks].u[q] = pack_bf16(wt[2 * q], wt[2 * q + 1]);
                bB[Nt][ks].u[q] = pack_bf16(wb[2 * q], wb[2 * q + 1]);
            }
        }
    }

    const int row0 = blockIdx.x * 64 + w * 16;
    if (row0 >= n_nodes) return;

    bfu aM[2], aN[2];
#pragma unroll
    for (int ks = 0; ks < 2; ++ks) {
        const int r = min(row0 + l15, n_nodes - 1);
        const float* __restrict__ pm = msum + (size_t)r * DO + ks * 32 + k0;
        const float* __restrict__ pn = node + (size_t)r * DN + ks * 32 + k0;
        const float4 m0 = *(const float4*)pm;
        const float4 m1 = *(const float4*)(pm + 4);
        const float4 n0 = *(const float4*)pn;
        const float4 n1 = *(const float4*)(pn + 4);
        aM[ks].u[0] = pack_bf16(m0.x, m0.y);
        aM[ks].u[1] = pack_bf16(m0.z, m0.w);
        aM[ks].u[2] = pack_bf16(m1.x, m1.y);
        aM[ks].u[3] = pack_bf16(m1.z, m1.w);
        aN[ks].u[0] = pack_bf16(n0.x, n0.y);
        aN[ks].u[1] = pack_bf16(n0.z, n0.w);
        aN[ks].u[2] = pack_bf16(n1.x, n1.y);
        aN[ks].u[3] = pack_bf16(n1.z, n1.w);
    }

    f32x4 accT[4], accB[4];
#pragma unroll
    for (int Nt = 0; Nt < 4; ++Nt) {
        const f32x4 z = {0.f, 0.f, 0.f, 0.f};
        f32x4 aT = __builtin_amdgcn_mfma_f32_16x16x32_bf16(aM[0].v, bT[Nt][0].v, z, 0, 0, 0);
        aT = __builtin_amdgcn_mfma_f32_16x16x32_bf16(aM[1].v, bT[Nt][1].v, aT, 0, 0, 0);
        f32x4 aB = __builtin_amdgcn_mfma_f32_16x16x32_bf16(aN[0].v, bB[Nt][0].v, z, 0, 0, 0);
        aB = __builtin_amdgcn_mfma_f32_16x16x32_bf16(aN[1].v, bB[Nt][1].v, aB, 0, 0, 0);
        accT[Nt] = aT;
        accB[Nt] = aB;
    }

    const int rb = row0 + ((lane >> 4) << 2);
#pragma unroll
    for (int r = 0; r < 4; ++r) {
        const int row = rb + r;
        if (row < n_nodes) {
            const float dg = (float)(row_start[row + 1] - row_start[row]);
            const float inv = (dg > 0.f) ? 1.f / dg : 0.f;
#pragma unroll
            for (int Nt = 0; Nt < 4; ++Nt) {
                const int col = (Nt << 4) | l15;
                const float val = accT[Nt][r] * inv + accB[Nt][r] + b_v[col];
                out[(size_t)row * DO + col] = fmaxf(val, 0.f);
            }
        }
    }
}

extern "C" void kernel_launch(void* const* d_in, const int* in_sizes, int n_in,
                              void* d_out, int out_size, void* d_ws, size_t ws_size,
                              hipStream_t stream)
{
    const float* node = (const float*)d_in[0];
    const float* edge = (const float*)d_in[1];
    const int*   src  = (const int*)d_in[2];
    const int*   dst  = (const int*)d_in[3];
    const float* W_e  = (const float*)d_in[4];
    const float* b_e  = (const float*)d_in[5];
    const float* W_v  = (const float*)d_in[6];
    const float* b_v  = (const float*)d_in[7];
    float* out = (float*)d_out;

    int n_nodes = in_sizes[0] / DN;
    int n_edges = in_sizes[2];
    const int ntiles  = (n_nodes + 63) / 64;

    // Workspace: PsB | PdB (bf16) | msum | cnt (contiguous: one memset) |
    //            row_start | local | bsum | rank | csr(int2)
    unsigned short* PsB = (unsigned short*)d_ws;
    unsigned short* PdB = PsB + (size_t)n_nodes * DO;
    float* msum = (float*)(PdB + (size_t)n_nodes * DO);
    int* cnt       = (int*)(msum + (size_t)n_nodes * DO);
    int* row_start = cnt + n_nodes;
    int* local     = row_start + (n_nodes + 1);
    int* bsum      = local + n_nodes;
    int* rank_     = bsum + NB;
    int2* csr      = (int2*)(((size_t)(rank_ + n_edges) + 15) & ~(size_t)15);

    // one memset covers msum (n*DO floats) + cnt (n ints), contiguous
    hipMemsetAsync(msum, 0, ((size_t)n_nodes * DO + n_nodes) * sizeof(float), stream);

    pre_hist_kernel<<<ntiles, 256, 0, stream>>>(node, W_e, dst, PsB, PdB,
                                                cnt, rank_, n_nodes, n_edges);

    {
        void* args[] = { (void*)&dst, (void*)&src, (void*)&rank_, (void*)&cnt,
                         (void*)&local, (void*)&bsum, (void*)&row_start,
                         (void*)&csr, (void*)&n_nodes, (void*)&n_edges };
        hipLaunchCooperativeKernel((const void*)csr_coop_kernel,
                                   dim3(COOPB), dim3(256), args, 0, stream);
    }

    agg_mfma_kernel<<<(n_edges + TP - 1) / TP, 128, 0, stream>>>(edge, W_e, b_e, PsB, PdB,
                                                                 row_start, csr, msum, n_edges);
    node_out_kernel<<<ntiles, 256, 0, stream>>>(node, msum, row_start, W_v, b_v,
                                                out, n_nodes);
}

// Round 15
// 134.204 us; speedup vs baseline: 2.6707x; 2.6707x over previous
//
#include <hip/hip_runtime.h>

#define DN 64
#define DE 32
#define DO 64
#define NB 256   // scan phase-1 blocks (requires n_nodes <= NB*256)
#define TP 128   // CSR positions per agg block (2 waves x 64)
#define CH 8     // Ps prefetch chunk

typedef __attribute__((ext_vector_type(8))) short bf16x8;
typedef __attribute__((ext_vector_type(4))) float f32x4;

__device__ inline unsigned pack_bf16(float a, float b) {
    unsigned ua = __float_as_uint(a), ub = __float_as_uint(b);
    ua = (ua + 0x7fffu + ((ua >> 16) & 1u)) >> 16;     // RNE bf16
    ub = (ub + 0x7fffu + ((ub >> 16) & 1u)) >> 16;
    return ua | (ub << 16);
}
__device__ inline unsigned short bf16_1(float a) {
    unsigned u = __float_as_uint(a);
    return (unsigned short)((u + 0x7fffu + ((u >> 16) & 1u)) >> 16);
}
__device__ inline float bf16f(unsigned short v) {
    return __uint_as_float((unsigned)v << 16);
}

union bfu { unsigned u[4]; bf16x8 v; };

// ---------------------------------------------------------------------------
// K1: MFMA per-node projections (bf16 tables) + degree histogram WITH RANK.
// rank[e] = edge's index within its dst bucket (atomic return value) -> the
// scatter kernel becomes atomic-free.
// ---------------------------------------------------------------------------
__global__ void __launch_bounds__(256) pre_hist_kernel(
    const float* __restrict__ node, const float* __restrict__ W_e,
    const int* __restrict__ dst,
    unsigned short* __restrict__ PsB, unsigned short* __restrict__ PdB,
    int* __restrict__ cnt, int* __restrict__ rank_,
    int n_nodes, int n_edges)
{
    const int t    = threadIdx.x;
    const int lane = t & 63;
    const int w    = __builtin_amdgcn_readfirstlane((int)(t >> 6));
    const int l15  = lane & 15;
    const int k0   = (lane >> 4) << 3;

    bfu bS[4][2], bD[4][2];
#pragma unroll
    for (int Nt = 0; Nt < 4; ++Nt) {
        const int col = (Nt << 4) | l15;
#pragma unroll
        for (int ks = 0; ks < 2; ++ks) {
            float ws[8], wd[8];
#pragma unroll
            for (int e = 0; e < 8; ++e) {
                ws[e] = W_e[(ks * 32 + k0 + e) * DO + col];
                wd[e] = W_e[(96 + ks * 32 + k0 + e) * DO + col];
            }
#pragma unroll
            for (int q = 0; q < 4; ++q) {
                bS[Nt][ks].u[q] = pack_bf16(ws[2 * q], ws[2 * q + 1]);
                bD[Nt][ks].u[q] = pack_bf16(wd[2 * q], wd[2 * q + 1]);
            }
        }
    }

    const int row0 = blockIdx.x * 64 + w * 16;
    if (row0 < n_nodes) {
        bfu aF[2];
#pragma unroll
        for (int ks = 0; ks < 2; ++ks) {
            const int r = min(row0 + l15, n_nodes - 1);
            const float* __restrict__ p = node + (size_t)r * DN + ks * 32 + k0;
            const float4 f0 = *(const float4*)p;
            const float4 f1 = *(const float4*)(p + 4);
            aF[ks].u[0] = pack_bf16(f0.x, f0.y);
            aF[ks].u[1] = pack_bf16(f0.z, f0.w);
            aF[ks].u[2] = pack_bf16(f1.x, f1.y);
            aF[ks].u[3] = pack_bf16(f1.z, f1.w);
        }
        const int rb = row0 + ((lane >> 4) << 2);
#pragma unroll
        for (int Nt = 0; Nt < 4; ++Nt) {
            const f32x4 z = {0.f, 0.f, 0.f, 0.f};
            f32x4 aS = __builtin_amdgcn_mfma_f32_16x16x32_bf16(aF[0].v, bS[Nt][0].v, z, 0, 0, 0);
            aS = __builtin_amdgcn_mfma_f32_16x16x32_bf16(aF[1].v, bS[Nt][1].v, aS, 0, 0, 0);
            f32x4 aD = __builtin_amdgcn_mfma_f32_16x16x32_bf16(aF[0].v, bD[Nt][0].v, z, 0, 0, 0);
            aD = __builtin_amdgcn_mfma_f32_16x16x32_bf16(aF[1].v, bD[Nt][1].v, aD, 0, 0, 0);
            const int col = (Nt << 4) | l15;
#pragma unroll
            for (int r = 0; r < 4; ++r) {
                if (rb + r < n_nodes) {
                    PsB[(size_t)(rb + r) * DO + col] = bf16_1(aS[r]);
                    PdB[(size_t)(rb + r) * DO + col] = bf16_1(aD[r]);
                }
            }
        }
    }

    const int gt = blockIdx.x * blockDim.x + t;
    const int nt = gridDim.x * blockDim.x;
    for (int e = gt; e < n_edges; e += nt)
        rank_[e] = atomicAdd(&cnt[dst[e]], 1);
}

// ---------------------------------------------------------------------------
// K2: per-block local exclusive scan + block sums. Also zeroes msum
// (grid-stride float4) -- replaces the big memset, overlapping it with the
// scan's tiny footprint.
// ---------------------------------------------------------------------------
__global__ void __launch_bounds__(256) scan_partial(
    const int* __restrict__ cnt, int* __restrict__ local,
    int* __restrict__ bsum, float* __restrict__ msum, int n_nodes)
{
    const int C = (n_nodes + NB - 1) / NB;
    const int t = threadIdx.x, lane = t & 63, w = t >> 6;
    const int i = blockIdx.x * C + t;

    int v = (t < C && i < n_nodes) ? cnt[i] : 0;
    int incl = v;
#pragma unroll
    for (int off = 1; off < 64; off <<= 1) {
        int u = __shfl_up(incl, off, 64);
        if (lane >= off) incl += u;
    }
    __shared__ int ws[4], wo[4];
    if (lane == 63) ws[w] = incl;
    __syncthreads();
    if (t == 0) {
        int r = 0;
#pragma unroll
        for (int q = 0; q < 4; ++q) { wo[q] = r; r += ws[q]; }
        bsum[blockIdx.x] = r;
    }
    __syncthreads();
    if (t < C && i < n_nodes) local[i] = incl - v + wo[w];

    // zero msum: n_nodes*DO floats, float4 grid-stride
    const size_t nf4 = (size_t)n_nodes * DO / 4;
    float4* __restrict__ m4 = (float4*)msum;
    const size_t g0 = (size_t)blockIdx.x * blockDim.x + t;
    const size_t gs = (size_t)gridDim.x * blockDim.x;
    const float4 z4 = make_float4(0.f, 0.f, 0.f, 0.f);
    for (size_t j = g0; j < nf4; j += gs) m4[j] = z4;
}

// ---------------------------------------------------------------------------
// K3: merged bsum-scan + add -> row_start
// ---------------------------------------------------------------------------
__global__ void __launch_bounds__(256) scan_final(
    const int* __restrict__ local, const int* __restrict__ bsum,
    int* __restrict__ row_start, int n_nodes)
{
    const int t = threadIdx.x, lane = t & 63, w = t >> 6;
    int v = bsum[t];
    int incl = v;
#pragma unroll
    for (int off = 1; off < 64; off <<= 1) {
        int u = __shfl_up(incl, off, 64);
        if (lane >= off) incl += u;
    }
    __shared__ int ws[4], wo[4];
    if (lane == 63) ws[w] = incl;
    __syncthreads();
    if (t == 0) {
        int r = 0;
#pragma unroll
        for (int q = 0; q < 4; ++q) { wo[q] = r; r += ws[q]; }
    }
    __syncthreads();
    const int excl = incl - v + wo[w];

    __shared__ int blockoff;
    if (t == (int)blockIdx.x) blockoff = excl;
    if (blockIdx.x == NB - 1 && t == NB - 1) row_start[n_nodes] = excl + v;
    __syncthreads();

    const int C = (n_nodes + NB - 1) / NB;
    const int i = blockIdx.x * C + t;
    if (t < C && i < n_nodes)
        row_start[i] = local[i] + blockoff;
}

// ---------------------------------------------------------------------------
// K4: ATOMIC-FREE scatter: p = row_start[dst[e]] + rank[e]. Pure streaming
// reads (dst/src/rank coalesced) + one scattered 8B store.
// ---------------------------------------------------------------------------
__global__ void __launch_bounds__(256) scatter_kernel(
    const int* __restrict__ dst, const int* __restrict__ src,
    const int* __restrict__ rank_, const int* __restrict__ row_start,
    int2* __restrict__ csr, int n_edges)
{
    const int e = blockIdx.x * blockDim.x + threadIdx.x;
    if (e < n_edges) {
        const int d = dst[e];
        const int p = row_start[d] + rank_[e];
        csr[p] = make_int2(e, src[e] | (d << 16));
    }
}

// ---------------------------------------------------------------------------
// K5: MFMA edge-message + segment aggregation (R13 structure, unchanged).
// ---------------------------------------------------------------------------
__global__ void __launch_bounds__(128) agg_mfma_kernel(
    const float* __restrict__ edge,
    const float* __restrict__ W_e, const float* __restrict__ b_e,
    const unsigned short* __restrict__ PsB, const unsigned short* __restrict__ PdB,
    const int* __restrict__ row_start, const int2* __restrict__ csr,
    float* __restrict__ msum, int n_edges)
{
    __shared__ unsigned lds_m[2][32][68];   // 17.4 KB: bf16-paired raw scores

    const int t    = threadIdx.x;
    const int lane = t & 63;
    const int wid  = __builtin_amdgcn_readfirstlane((int)(t >> 6));
    const int wbeg = blockIdx.x * TP + wid * 64;
    const int wcnt = min(n_edges - wbeg, 64);
    if (wcnt <= 0) return;

    const int l15 = lane & 15;
    const int k0  = (lane >> 4) << 3;

    bfu bfr[4];
#pragma unroll
    for (int Nt = 0; Nt < 4; ++Nt) {
        const int col = (Nt << 4) | l15;
        float wv[8];
#pragma unroll
        for (int e = 0; e < 8; ++e)
            wv[e] = W_e[(64 + k0 + e) * DO + col];
#pragma unroll
        for (int v2 = 0; v2 < 4; ++v2)
            bfr[Nt].u[v2] = pack_bf16(wv[2 * v2], wv[2 * v2 + 1]);
    }
    const float bj = b_e[lane];

    const int2 my2 = csr[min(wbeg + lane, n_edges - 1)];

#pragma unroll
    for (int Mt = 0; Mt < 4; ++Mt) {
        const int eA = __shfl(my2.x, (Mt << 4) | l15, 64);
        const float* __restrict__ ep = edge + (size_t)(unsigned)eA * DE + k0;
        const float4 f0 = *(const float4*)(ep);
        const float4 f1 = *(const float4*)(ep + 4);
        bfu afr;
        afr.u[0] = pack_bf16(f0.x, f0.y);
        afr.u[1] = pack_bf16(f0.z, f0.w);
        afr.u[2] = pack_bf16(f1.x, f1.y);
        afr.u[3] = pack_bf16(f1.z, f1.w);
        const int rp0 = (Mt << 3) + ((lane >> 4) << 1);
#pragma unroll
        for (int Nt = 0; Nt < 4; ++Nt) {
            f32x4 dz = {0.f, 0.f, 0.f, 0.f};
            f32x4 d = __builtin_amdgcn_mfma_f32_16x16x32_bf16(afr.v, bfr[Nt].v, dz, 0, 0, 0);
            const int col = (Nt << 4) | l15;
            lds_m[wid][rp0][col]     = pack_bf16(d[0], d[1]);
            lds_m[wid][rp0 + 1][col] = pack_bf16(d[2], d[3]);
        }
    }

    float acc = 0.f, bpd = 0.f;
    int cur_d = -1;

#define FLUSH()                                                         \
    {                                                                   \
        if (row_start[cur_d] >= wbeg)                                   \
            msum[(size_t)cur_d * DO + lane] = acc;                      \
        else                                                            \
            unsafeAtomicAdd(&msum[(size_t)cur_d * DO + lane], acc);     \
    }

#define ISSUE(CHK, BUF)                                                 \
    _Pragma("unroll")                                                   \
    for (int q = 0; q < CH; ++q) {                                      \
        const int y = __builtin_amdgcn_readlane(my2.y, (CHK) * CH + q); \
        BUF[q] = PsB[(size_t)(unsigned)(y & 0xffff) * DO + lane];       \
    }

#define CONSUME(CHK, BUF)                                               \
    {                                                                   \
        unsigned um[4];                                                 \
        _Pragma("unroll")                                               \
        for (int h = 0; h < 4; ++h)                                     \
            um[h] = lds_m[wid][(CHK) * 4 + h][lane];                    \
        _Pragma("unroll")                                               \
        for (int q = 0; q < CH; ++q) {                                  \
            const int y = __builtin_amdgcn_readlane(my2.y, (CHK) * CH + q); \
            const int d = (int)(((unsigned)y) >> 16);                   \
            if (d != cur_d) {                                           \
                if (cur_d >= 0) FLUSH();                                \
                acc = 0.f;                                              \
                cur_d = d;                                              \
                bpd = bj + bf16f(PdB[(size_t)(unsigned)d * DO + lane]); \
            }                                                           \
            const unsigned u = um[q >> 1];                              \
            const float mv = (q & 1) ? __uint_as_float(u & 0xffff0000u) \
                                     : __uint_as_float(u << 16);        \
            acc += fmaxf(mv + bpd + __uint_as_float((unsigned)BUF[q] << 16), 0.f); \
        }                                                               \
    }

    if (wcnt == 64) {
        unsigned short pnA[CH], pnB[CH], pnC[CH];
        ISSUE(0, pnA) ISSUE(1, pnB)
        ISSUE(2, pnC) CONSUME(0, pnA)
        ISSUE(3, pnA) CONSUME(1, pnB)
        ISSUE(4, pnB) CONSUME(2, pnC)
        ISSUE(5, pnC) CONSUME(3, pnA)
        ISSUE(6, pnA) CONSUME(4, pnB)
        ISSUE(7, pnB) CONSUME(5, pnC)
        CONSUME(6, pnA)
        CONSUME(7, pnB)
    } else {
        for (int p = 0; p < wcnt; ++p) {
            const int y = __builtin_amdgcn_readlane(my2.y, p);
            const int s = y & 0xffff;
            const int d = (int)(((unsigned)y) >> 16);
            const float ps = bf16f(PsB[(size_t)(unsigned)s * DO + lane]);
            if (d != cur_d) {
                if (cur_d >= 0) FLUSH();
                acc = 0.f;
                cur_d = d;
                bpd = bj + bf16f(PdB[(size_t)(unsigned)d * DO + lane]);
            }
            const unsigned u = lds_m[wid][p >> 1][lane];
            const float mv = (p & 1) ? __uint_as_float(u & 0xffff0000u)
                                     : __uint_as_float(u << 16);
            acc += fmaxf(mv + bpd + ps, 0.f);
        }
    }

    {   // final flush
        const int sb = row_start[cur_d];
        const int se = row_start[cur_d + 1];
        if (sb >= wbeg && se <= wbeg + wcnt)
            msum[(size_t)cur_d * DO + lane] = acc;
        else
            unsafeAtomicAdd(&msum[(size_t)cur_d * DO + lane], acc);
    }
#undef FLUSH
#undef ISSUE
#undef CONSUME
}

// ---------------------------------------------------------------------------
// K6: MFMA node update: out = relu((msum@Wt)/deg + node@Wb + b_v).
// ---------------------------------------------------------------------------
__global__ void __launch_bounds__(256) node_out_kernel(
    const float* __restrict__ node, const float* __restrict__ msum,
    const int* __restrict__ row_start,
    const float* __restrict__ W_v, const float* __restrict__ b_v,
    float* __restrict__ out, int n_nodes)
{
    const int t    = threadIdx.x;
    const int lane = t & 63;
    const int w    = __builtin_amdgcn_readfirstlane((int)(t >> 6));
    const int l15  = lane & 15;
    const int k0   = (lane >> 4) << 3;

    bfu bT[4][2], bB[4][2];
#pragma unroll
    for (int Nt = 0; Nt < 4; ++Nt) {
        const int col = (Nt << 4) | l15;
#pragma unroll
        for (int ks = 0; ks < 2; ++ks) {
            float wt[8], wb[8];
#pragma unroll
            for (int e = 0; e < 8; ++e) {
                wt[e] = W_v[(ks * 32 + k0 + e) * DO + col];
                wb[e] = W_v[(64 + ks * 32 + k0 + e) * DO + col];
            }
#pragma unroll
            for (int q = 0; q < 4; ++q) {
                bT[Nt][ks].u[q] = pack_bf16(wt[2 * q], wt[2 * q + 1]);
                bB[Nt][ks].u[q] = pack_bf16(wb[2 * q], wb[2 * q + 1]);
            }
        }
    }

    const int row0 = blockIdx.x * 64 + w * 16;
    if (row0 >= n_nodes) return;

    bfu aM[2], aN[2];
#pragma unroll
    for (int ks = 0; ks < 2; ++ks) {
        const int r = min(row0 + l15, n_nodes - 1);
        const float* __restrict__ pm = msum + (size_t)r * DO + ks * 32 + k0;
        const float* __restrict__ pn = node + (size_t)r * DN + ks * 32 + k0;
        const float4 m0 = *(const float4*)pm;
        const float4 m1 = *(const float4*)(pm + 4);
        const float4 n0 = *(const float4*)pn;
        const float4 n1 = *(const float4*)(pn + 4);
        aM[ks].u[0] = pack_bf16(m0.x, m0.y);
        aM[ks].u[1] = pack_bf16(m0.z, m0.w);
        aM[ks].u[2] = pack_bf16(m1.x, m1.y);
        aM[ks].u[3] = pack_bf16(m1.z, m1.w);
        aN[ks].u[0] = pack_bf16(n0.x, n0.y);
        aN[ks].u[1] = pack_bf16(n0.z, n0.w);
        aN[ks].u[2] = pack_bf16(n1.x, n1.y);
        aN[ks].u[3] = pack_bf16(n1.z, n1.w);
    }

    f32x4 accT[4], accB[4];
#pragma unroll
    for (int Nt = 0; Nt < 4; ++Nt) {
        const f32x4 z = {0.f, 0.f, 0.f, 0.f};
        f32x4 aT = __builtin_amdgcn_mfma_f32_16x16x32_bf16(aM[0].v, bT[Nt][0].v, z, 0, 0, 0);
        aT = __builtin_amdgcn_mfma_f32_16x16x32_bf16(aM[1].v, bT[Nt][1].v, aT, 0, 0, 0);
        f32x4 aB = __builtin_amdgcn_mfma_f32_16x16x32_bf16(aN[0].v, bB[Nt][0].v, z, 0, 0, 0);
        aB = __builtin_amdgcn_mfma_f32_16x16x32_bf16(aN[1].v, bB[Nt][1].v, aB, 0, 0, 0);
        accT[Nt] = aT;
        accB[Nt] = aB;
    }

    const int rb = row0 + ((lane >> 4) << 2);
#pragma unroll
    for (int r = 0; r < 4; ++r) {
        const int row = rb + r;
        if (row < n_nodes) {
            const float dg = (float)(row_start[row + 1] - row_start[row]);
            const float inv = (dg > 0.f) ? 1.f / dg : 0.f;
#pragma unroll
            for (int Nt = 0; Nt < 4; ++Nt) {
                const int col = (Nt << 4) | l15;
                const float val = accT[Nt][r] * inv + accB[Nt][r] + b_v[col];
                out[(size_t)row * DO + col] = fmaxf(val, 0.f);
            }
        }
    }
}

extern "C" void kernel_launch(void* const* d_in, const int* in_sizes, int n_in,
                              void* d_out, int out_size, void* d_ws, size_t ws_size,
                              hipStream_t stream)
{
    const float* node = (const float*)d_in[0];
    const float* edge = (const float*)d_in[1];
    const int*   src  = (const int*)d_in[2];
    const int*   dst  = (const int*)d_in[3];
    const float* W_e  = (const float*)d_in[4];
    const float* b_e  = (const float*)d_in[5];
    const float* W_v  = (const float*)d_in[6];
    const float* b_v  = (const float*)d_in[7];
    float* out = (float*)d_out;

    const int n_nodes = in_sizes[0] / DN;
    const int n_edges = in_sizes[2];
    const int ntiles  = (n_nodes + 63) / 64;

    // Workspace: PsB | PdB (bf16) | msum | cnt | row_start | local | bsum |
    //            rank | csr(int2)
    unsigned short* PsB = (unsigned short*)d_ws;
    unsigned short* PdB = PsB + (size_t)n_nodes * DO;
    float* msum = (float*)(PdB + (size_t)n_nodes * DO);
    int* cnt       = (int*)(msum + (size_t)n_nodes * DO);
    int* row_start = cnt + n_nodes;
    int* local     = row_start + (n_nodes + 1);
    int* bsum      = local + n_nodes;
    int* rank_     = bsum + NB;
    int2* csr      = (int2*)(((size_t)(rank_ + n_edges) + 15) & ~(size_t)15);

    // only cnt needs zeroing up-front; msum is zeroed inside scan_partial
    hipMemsetAsync(cnt, 0, (size_t)n_nodes * sizeof(int), stream);

    pre_hist_kernel<<<ntiles, 256, 0, stream>>>(node, W_e, dst, PsB, PdB,
                                                cnt, rank_, n_nodes, n_edges);
    scan_partial<<<NB, 256, 0, stream>>>(cnt, local, bsum, msum, n_nodes);
    scan_final<<<NB, 256, 0, stream>>>(local, bsum, row_start, n_nodes);
    scatter_kernel<<<(n_edges + 255) / 256, 256, 0, stream>>>(dst, src, rank_, row_start,
                                                              csr, n_edges);
    agg_mfma_kernel<<<(n_edges + TP - 1) / TP, 128, 0, stream>>>(edge, W_e, b_e, PsB, PdB,
                                                                 row_start, csr, msum, n_edges);
    node_out_kernel<<<ntiles, 256, 0, stream>>>(node, msum, row_start, W_v, b_v,
                                                out, n_nodes);
}

// Round 16
// 133.418 us; speedup vs baseline: 2.6864x; 1.0059x over previous
//
#include <hip/hip_runtime.h>

#define DN 64
#define DE 32
#define DO 64
#define NB 256   // scan phase-1 blocks (requires n_nodes <= NB*256)
#define TP 128   // CSR positions per agg block (2 waves x 64)
#define CH 8     // Ps prefetch chunk

typedef __attribute__((ext_vector_type(8))) short bf16x8;
typedef __attribute__((ext_vector_type(4))) float f32x4;

__device__ inline unsigned pack_bf16(float a, float b) {
    unsigned ua = __float_as_uint(a), ub = __float_as_uint(b);
    ua = (ua + 0x7fffu + ((ua >> 16) & 1u)) >> 16;     // RNE bf16
    ub = (ub + 0x7fffu + ((ub >> 16) & 1u)) >> 16;
    return ua | (ub << 16);
}
__device__ inline unsigned short bf16_1(float a) {
    unsigned u = __float_as_uint(a);
    return (unsigned short)((u + 0x7fffu + ((u >> 16) & 1u)) >> 16);
}
__device__ inline float bf16f(unsigned short v) {
    return __uint_as_float((unsigned)v << 16);
}

union bfu { unsigned u[4]; bf16x8 v; };

// ---------------------------------------------------------------------------
// K1: MFMA per-node projections (bf16 tables) + degree histogram WITH RANK.
// ---------------------------------------------------------------------------
__global__ void __launch_bounds__(256) pre_hist_kernel(
    const float* __restrict__ node, const float* __restrict__ W_e,
    const int* __restrict__ dst,
    unsigned short* __restrict__ PsB, unsigned short* __restrict__ PdB,
    int* __restrict__ cnt, int* __restrict__ rank_,
    int n_nodes, int n_edges)
{
    const int t    = threadIdx.x;
    const int lane = t & 63;
    const int w    = __builtin_amdgcn_readfirstlane((int)(t >> 6));
    const int l15  = lane & 15;
    const int k0   = (lane >> 4) << 3;

    bfu bS[4][2], bD[4][2];
#pragma unroll
    for (int Nt = 0; Nt < 4; ++Nt) {
        const int col = (Nt << 4) | l15;
#pragma unroll
        for (int ks = 0; ks < 2; ++ks) {
            float ws[8], wd[8];
#pragma unroll
            for (int e = 0; e < 8; ++e) {
                ws[e] = W_e[(ks * 32 + k0 + e) * DO + col];
                wd[e] = W_e[(96 + ks * 32 + k0 + e) * DO + col];
            }
#pragma unroll
            for (int q = 0; q < 4; ++q) {
                bS[Nt][ks].u[q] = pack_bf16(ws[2 * q], ws[2 * q + 1]);
                bD[Nt][ks].u[q] = pack_bf16(wd[2 * q], wd[2 * q + 1]);
            }
        }
    }

    const int row0 = blockIdx.x * 64 + w * 16;
    if (row0 < n_nodes) {
        bfu aF[2];
#pragma unroll
        for (int ks = 0; ks < 2; ++ks) {
            const int r = min(row0 + l15, n_nodes - 1);
            const float* __restrict__ p = node + (size_t)r * DN + ks * 32 + k0;
            const float4 f0 = *(const float4*)p;
            const float4 f1 = *(const float4*)(p + 4);
            aF[ks].u[0] = pack_bf16(f0.x, f0.y);
            aF[ks].u[1] = pack_bf16(f0.z, f0.w);
            aF[ks].u[2] = pack_bf16(f1.x, f1.y);
            aF[ks].u[3] = pack_bf16(f1.z, f1.w);
        }
        const int rb = row0 + ((lane >> 4) << 2);
#pragma unroll
        for (int Nt = 0; Nt < 4; ++Nt) {
            const f32x4 z = {0.f, 0.f, 0.f, 0.f};
            f32x4 aS = __builtin_amdgcn_mfma_f32_16x16x32_bf16(aF[0].v, bS[Nt][0].v, z, 0, 0, 0);
            aS = __builtin_amdgcn_mfma_f32_16x16x32_bf16(aF[1].v, bS[Nt][1].v, aS, 0, 0, 0);
            f32x4 aD = __builtin_amdgcn_mfma_f32_16x16x32_bf16(aF[0].v, bD[Nt][0].v, z, 0, 0, 0);
            aD = __builtin_amdgcn_mfma_f32_16x16x32_bf16(aF[1].v, bD[Nt][1].v, aD, 0, 0, 0);
            const int col = (Nt << 4) | l15;
#pragma unroll
            for (int r = 0; r < 4; ++r) {
                if (rb + r < n_nodes) {
                    PsB[(size_t)(rb + r) * DO + col] = bf16_1(aS[r]);
                    PdB[(size_t)(rb + r) * DO + col] = bf16_1(aD[r]);
                }
            }
        }
    }

    const int gt = blockIdx.x * blockDim.x + t;
    const int nt = gridDim.x * blockDim.x;
    for (int e = gt; e < n_edges; e += nt)
        rank_[e] = atomicAdd(&cnt[dst[e]], 1);
}

// ---------------------------------------------------------------------------
// K2: per-block local exclusive scan + block sums; also zeroes msum.
// ---------------------------------------------------------------------------
__global__ void __launch_bounds__(256) scan_partial(
    const int* __restrict__ cnt, int* __restrict__ local,
    int* __restrict__ bsum, float* __restrict__ msum, int n_nodes)
{
    const int C = (n_nodes + NB - 1) / NB;
    const int t = threadIdx.x, lane = t & 63, w = t >> 6;
    const int i = blockIdx.x * C + t;

    int v = (t < C && i < n_nodes) ? cnt[i] : 0;
    int incl = v;
#pragma unroll
    for (int off = 1; off < 64; off <<= 1) {
        int u = __shfl_up(incl, off, 64);
        if (lane >= off) incl += u;
    }
    __shared__ int ws[4], wo[4];
    if (lane == 63) ws[w] = incl;
    __syncthreads();
    if (t == 0) {
        int r = 0;
#pragma unroll
        for (int q = 0; q < 4; ++q) { wo[q] = r; r += ws[q]; }
        bsum[blockIdx.x] = r;
    }
    __syncthreads();
    if (t < C && i < n_nodes) local[i] = incl - v + wo[w];

    const size_t nf4 = (size_t)n_nodes * DO / 4;
    float4* __restrict__ m4 = (float4*)msum;
    const size_t g0 = (size_t)blockIdx.x * blockDim.x + t;
    const size_t gs = (size_t)gridDim.x * blockDim.x;
    const float4 z4 = make_float4(0.f, 0.f, 0.f, 0.f);
    for (size_t j = g0; j < nf4; j += gs) m4[j] = z4;
}

// ---------------------------------------------------------------------------
// K3: merged scan_final + scatter. Every block redundantly shfl-scans the
// NB block sums (L2-hot, ~200 cyc); row_start[d] = local[d] + boff[d/C].
// First NB blocks also materialize row_start for agg/node_out. Scatter is
// atomic-free: p = row_start[d] + rank[e].
// ---------------------------------------------------------------------------
__global__ void __launch_bounds__(256) scatter_scan_kernel(
    const int* __restrict__ dst, const int* __restrict__ src,
    const int* __restrict__ rank_, const int* __restrict__ local,
    const int* __restrict__ bsum,
    int* __restrict__ row_start, int2* __restrict__ csr,
    int n_nodes, int n_edges, int C)
{
    __shared__ int boff[NB];
    const int t = threadIdx.x, lane = t & 63, w = t >> 6;

    {   // redundant per-block exclusive scan of bsum[0..NB)
        int v = bsum[t];
        int incl = v;
#pragma unroll
        for (int off = 1; off < 64; off <<= 1) {
            int u = __shfl_up(incl, off, 64);
            if (lane >= off) incl += u;
        }
        __shared__ int ws[4], wo[4];
        if (lane == 63) ws[w] = incl;
        __syncthreads();
        if (t == 0) {
            int r = 0;
#pragma unroll
            for (int q = 0; q < 4; ++q) { wo[q] = r; r += ws[q]; }
        }
        __syncthreads();
        boff[t] = incl - v + wo[w];
    }
    __syncthreads();

    if (blockIdx.x < NB) {      // materialize row_start
        const int i = blockIdx.x * C + t;
        if (t < C && i < n_nodes) row_start[i] = local[i] + boff[blockIdx.x];
        if (blockIdx.x == 0 && t == 0) row_start[n_nodes] = n_edges;
    }

    const int e = blockIdx.x * blockDim.x + t;
    if (e < n_edges) {
        const int d = dst[e];
        const int p = local[d] + boff[(unsigned)d / (unsigned)C] + rank_[e];
        csr[p] = make_int2(e, src[e] | (d << 16));
    }
}

// ---------------------------------------------------------------------------
// K4: MFMA edge-message + segment aggregation, HALF-SPLIT score buffer.
// LDS per wave = 16 row-pairs (32 positions) instead of 32: 8.7 KB/block ->
// 16 blocks/CU (thread cap) = 32 waves/CU (was 9 blocks/18 waves at 17.4KB).
// Schedule: MFMA half0 -> walk 0..31 (Ps chunk-prefetched) -> MFMA half1 ->
// walk 32..63. Intra-wave serialization covered by doubled TLP.
// ---------------------------------------------------------------------------
__global__ void __launch_bounds__(128) agg_mfma_kernel(
    const float* __restrict__ edge,
    const float* __restrict__ W_e, const float* __restrict__ b_e,
    const unsigned short* __restrict__ PsB, const unsigned short* __restrict__ PdB,
    const int* __restrict__ row_start, const int2* __restrict__ csr,
    float* __restrict__ msum, int n_edges)
{
    __shared__ unsigned lds_m[2][16][68];   // 8.7 KB: bf16-paired scores (half)

    const int t    = threadIdx.x;
    const int lane = t & 63;
    const int wid  = __builtin_amdgcn_readfirstlane((int)(t >> 6));
    const int wbeg = blockIdx.x * TP + wid * 64;
    const int wcnt = min(n_edges - wbeg, 64);
    if (wcnt <= 0) return;

    const int l15 = lane & 15;
    const int k0  = (lane >> 4) << 3;

    bfu bfr[4];
#pragma unroll
    for (int Nt = 0; Nt < 4; ++Nt) {
        const int col = (Nt << 4) | l15;
        float wv[8];
#pragma unroll
        for (int e = 0; e < 8; ++e)
            wv[e] = W_e[(64 + k0 + e) * DO + col];
#pragma unroll
        for (int v2 = 0; v2 < 4; ++v2)
            bfr[Nt].u[v2] = pack_bf16(wv[2 * v2], wv[2 * v2 + 1]);
    }
    const float bj = b_e[lane];

    const int2 my2 = csr[min(wbeg + lane, n_edges - 1)];

    float acc = 0.f, bpd = 0.f;
    int cur_d = -1;

// MFMA for half H (Mt = 2H, 2H+1) -> lds_m[wid][0..15][*]
#define MFMA_HALF(H)                                                          \
    _Pragma("unroll")                                                         \
    for (int Mt = 2 * (H); Mt < 2 * (H) + 2; ++Mt) {                          \
        const int eA = __shfl(my2.x, (Mt << 4) | l15, 64);                    \
        const float* __restrict__ ep = edge + (size_t)(unsigned)eA * DE + k0; \
        const float4 f0 = *(const float4*)(ep);                               \
        const float4 f1 = *(const float4*)(ep + 4);                           \
        bfu afr;                                                              \
        afr.u[0] = pack_bf16(f0.x, f0.y);                                     \
        afr.u[1] = pack_bf16(f0.z, f0.w);                                     \
        afr.u[2] = pack_bf16(f1.x, f1.y);                                     \
        afr.u[3] = pack_bf16(f1.z, f1.w);                                     \
        const int rp0 = ((Mt & 1) << 3) + ((lane >> 4) << 1);                 \
        _Pragma("unroll")                                                     \
        for (int Nt = 0; Nt < 4; ++Nt) {                                      \
            f32x4 dz = {0.f, 0.f, 0.f, 0.f};                                  \
            f32x4 d = __builtin_amdgcn_mfma_f32_16x16x32_bf16(afr.v, bfr[Nt].v, dz, 0, 0, 0); \
            const int col = (Nt << 4) | l15;                                  \
            lds_m[wid][rp0][col]     = pack_bf16(d[0], d[1]);                 \
            lds_m[wid][rp0 + 1][col] = pack_bf16(d[2], d[3]);                 \
        }                                                                     \
    }

#define FLUSH()                                                         \
    {                                                                   \
        if (row_start[cur_d] >= wbeg)                                   \
            msum[(size_t)cur_d * DO + lane] = acc;                      \
        else                                                            \
            unsafeAtomicAdd(&msum[(size_t)cur_d * DO + lane], acc);     \
    }

#define ISSUE(CHK, BUF)                                                 \
    _Pragma("unroll")                                                   \
    for (int q = 0; q < CH; ++q) {                                      \
        const int y = __builtin_amdgcn_readlane(my2.y, (CHK) * CH + q); \
        BUF[q] = PsB[(size_t)(unsigned)(y & 0xffff) * DO + lane];       \
    }

// CHK is global chunk 0..7; half-local row-pair base = (CHK&3)*4
#define CONSUME(CHK, BUF)                                               \
    {                                                                   \
        unsigned um[4];                                                 \
        _Pragma("unroll")                                               \
        for (int h = 0; h < 4; ++h)                                     \
            um[h] = lds_m[wid][((CHK) & 3) * 4 + h][lane];              \
        _Pragma("unroll")                                               \
        for (int q = 0; q < CH; ++q) {                                  \
            const int y = __builtin_amdgcn_readlane(my2.y, (CHK) * CH + q); \
            const int d = (int)(((unsigned)y) >> 16);                   \
            if (d != cur_d) {                                           \
                if (cur_d >= 0) FLUSH();                                \
                acc = 0.f;                                              \
                cur_d = d;                                              \
                bpd = bj + bf16f(PdB[(size_t)(unsigned)d * DO + lane]); \
            }                                                           \
            const unsigned u = um[q >> 1];                              \
            const float mv = (q & 1) ? __uint_as_float(u & 0xffff0000u) \
                                     : __uint_as_float(u << 16);        \
            acc += fmaxf(mv + bpd + __uint_as_float((unsigned)BUF[q] << 16), 0.f); \
        }                                                               \
    }

    if (wcnt == 64) {
        unsigned short pnA[CH], pnB[CH], pnC[CH];
        MFMA_HALF(0)
        ISSUE(0, pnA) ISSUE(1, pnB) ISSUE(2, pnC)
        CONSUME(0, pnA)
        ISSUE(3, pnA) CONSUME(1, pnB)
        ISSUE(4, pnB) CONSUME(2, pnC)
        ISSUE(5, pnC) CONSUME(3, pnA)
        MFMA_HALF(1)
        ISSUE(6, pnA) CONSUME(4, pnB)
        ISSUE(7, pnB) CONSUME(5, pnC)
        CONSUME(6, pnA)
        CONSUME(7, pnB)
    } else {
        for (int h = 0; h < 2; ++h) {
            const int p0 = h * 32;
            if (p0 >= wcnt) break;
            MFMA_HALF(h)
            const int pe = min(wcnt, p0 + 32);
            for (int p = p0; p < pe; ++p) {
                const int y = __builtin_amdgcn_readlane(my2.y, p);
                const int s = y & 0xffff;
                const int d = (int)(((unsigned)y) >> 16);
                const float ps = bf16f(PsB[(size_t)(unsigned)s * DO + lane]);
                if (d != cur_d) {
                    if (cur_d >= 0) FLUSH();
                    acc = 0.f;
                    cur_d = d;
                    bpd = bj + bf16f(PdB[(size_t)(unsigned)d * DO + lane]);
                }
                const unsigned u = lds_m[wid][(p & 31) >> 1][lane];
                const float mv = (p & 1) ? __uint_as_float(u & 0xffff0000u)
                                         : __uint_as_float(u << 16);
                acc += fmaxf(mv + bpd + ps, 0.f);
            }
        }
    }

    {   // final flush
        const int sb = row_start[cur_d];
        const int se = row_start[cur_d + 1];
        if (sb >= wbeg && se <= wbeg + wcnt)
            msum[(size_t)cur_d * DO + lane] = acc;
        else
            unsafeAtomicAdd(&msum[(size_t)cur_d * DO + lane], acc);
    }
#undef MFMA_HALF
#undef FLUSH
#undef ISSUE
#undef CONSUME
}

// ---------------------------------------------------------------------------
// K5: MFMA node update: out = relu((msum@Wt)/deg + node@Wb + b_v).
// ---------------------------------------------------------------------------
__global__ void __launch_bounds__(256) node_out_kernel(
    const float* __restrict__ node, const float* __restrict__ msum,
    const int* __restrict__ row_start,
    const float* __restrict__ W_v, const float* __restrict__ b_v,
    float* __restrict__ out, int n_nodes)
{
    const int t    = threadIdx.x;
    const int lane = t & 63;
    const int w    = __builtin_amdgcn_readfirstlane((int)(t >> 6));
    const int l15  = lane & 15;
    const int k0   = (lane >> 4) << 3;

    bfu bT[4][2], bB[4][2];
#pragma unroll
    for (int Nt = 0; Nt < 4; ++Nt) {
        const int col = (Nt << 4) | l15;
#pragma unroll
        for (int ks = 0; ks < 2; ++ks) {
            float wt[8], wb[8];
#pragma unroll
            for (int e = 0; e < 8; ++e) {
                wt[e] = W_v[(ks * 32 + k0 + e) * DO + col];
                wb[e] = W_v[(64 + ks * 32 + k0 + e) * DO + col];
            }
#pragma unroll
            for (int q = 0; q < 4; ++q) {
                bT[Nt][ks].u[q] = pack_bf16(wt[2 * q], wt[2 * q + 1]);
                bB[Nt][ks].u[q] = pack_bf16(wb[2 * q], wb[2 * q + 1]);
            }
        }
    }

    const int row0 = blockIdx.x * 64 + w * 16;
    if (row0 >= n_nodes) return;

    bfu aM[2], aN[2];
#pragma unroll
    for (int ks = 0; ks < 2; ++ks) {
        const int r = min(row0 + l15, n_nodes - 1);
        const float* __restrict__ pm = msum + (size_t)r * DO + ks * 32 + k0;
        const float* __restrict__ pn = node + (size_t)r * DN + ks * 32 + k0;
        const float4 m0 = *(const float4*)pm;
        const float4 m1 = *(const float4*)(pm + 4);
        const float4 n0 = *(const float4*)pn;
        const float4 n1 = *(const float4*)(pn + 4);
        aM[ks].u[0] = pack_bf16(m0.x, m0.y);
        aM[ks].u[1] = pack_bf16(m0.z, m0.w);
        aM[ks].u[2] = pack_bf16(m1.x, m1.y);
        aM[ks].u[3] = pack_bf16(m1.z, m1.w);
        aN[ks].u[0] = pack_bf16(n0.x, n0.y);
        aN[ks].u[1] = pack_bf16(n0.z, n0.w);
        aN[ks].u[2] = pack_bf16(n1.x, n1.y);
        aN[ks].u[3] = pack_bf16(n1.z, n1.w);
    }

    f32x4 accT[4], accB[4];
#pragma unroll
    for (int Nt = 0; Nt < 4; ++Nt) {
        const f32x4 z = {0.f, 0.f, 0.f, 0.f};
        f32x4 aT = __builtin_amdgcn_mfma_f32_16x16x32_bf16(aM[0].v, bT[Nt][0].v, z, 0, 0, 0);
        aT = __builtin_amdgcn_mfma_f32_16x16x32_bf16(aM[1].v, bT[Nt][1].v, aT, 0, 0, 0);
        f32x4 aB = __builtin_amdgcn_mfma_f32_16x16x32_bf16(aN[0].v, bB[Nt][0].v, z, 0, 0, 0);
        aB = __builtin_amdgcn_mfma_f32_16x16x32_bf16(aN[1].v, bB[Nt][1].v, aB, 0, 0, 0);
        accT[Nt] = aT;
        accB[Nt] = aB;
    }

    const int rb = row0 + ((lane >> 4) << 2);
#pragma unroll
    for (int r = 0; r < 4; ++r) {
        const int row = rb + r;
        if (row < n_nodes) {
            const float dg = (float)(row_start[row + 1] - row_start[row]);
            const float inv = (dg > 0.f) ? 1.f / dg : 0.f;
#pragma unroll
            for (int Nt = 0; Nt < 4; ++Nt) {
                const int col = (Nt << 4) | l15;
                const float val = accT[Nt][r] * inv + accB[Nt][r] + b_v[col];
                out[(size_t)row * DO + col] = fmaxf(val, 0.f);
            }
        }
    }
}

extern "C" void kernel_launch(void* const* d_in, const int* in_sizes, int n_in,
                              void* d_out, int out_size, void* d_ws, size_t ws_size,
                              hipStream_t stream)
{
    const float* node = (const float*)d_in[0];
    const float* edge = (const float*)d_in[1];
    const int*   src  = (const int*)d_in[2];
    const int*   dst  = (const int*)d_in[3];
    const float* W_e  = (const float*)d_in[4];
    const float* b_e  = (const float*)d_in[5];
    const float* W_v  = (const float*)d_in[6];
    const float* b_v  = (const float*)d_in[7];
    float* out = (float*)d_out;

    const int n_nodes = in_sizes[0] / DN;
    const int n_edges = in_sizes[2];
    const int ntiles  = (n_nodes + 63) / 64;
    const int C       = (n_nodes + NB - 1) / NB;

    // Workspace: PsB | PdB (bf16) | msum | cnt | row_start | local | bsum |
    //            rank | csr(int2)
    unsigned short* PsB = (unsigned short*)d_ws;
    unsigned short* PdB = PsB + (size_t)n_nodes * DO;
    float* msum = (float*)(PdB + (size_t)n_nodes * DO);
    int* cnt       = (int*)(msum + (size_t)n_nodes * DO);
    int* row_start = cnt + n_nodes;
    int* local     = row_start + (n_nodes + 1);
    int* bsum      = local + n_nodes;
    int* rank_     = bsum + NB;
    int2* csr      = (int2*)(((size_t)(rank_ + n_edges) + 15) & ~(size_t)15);

    hipMemsetAsync(cnt, 0, (size_t)n_nodes * sizeof(int), stream);

    pre_hist_kernel<<<ntiles, 256, 0, stream>>>(node, W_e, dst, PsB, PdB,
                                                cnt, rank_, n_nodes, n_edges);
    scan_partial<<<NB, 256, 0, stream>>>(cnt, local, bsum, msum, n_nodes);
    scatter_scan_kernel<<<(n_edges + 255) / 256, 256, 0, stream>>>(
        dst, src, rank_, local, bsum, row_start, csr, n_nodes, n_edges, C);
    agg_mfma_kernel<<<(n_edges + TP - 1) / TP, 128, 0, stream>>>(edge, W_e, b_e, PsB, PdB,
                                                                 row_start, csr, msum, n_edges);
    node_out_kernel<<<ntiles, 256, 0, stream>>>(node, msum, row_start, W_v, b_v,
                                                out, n_nodes);
}

// Round 17
// 132.631 us; speedup vs baseline: 2.7024x; 1.0059x over previous
//
#include <hip/hip_runtime.h>

#define DN 64
#define DE 32
#define DO 64
#define NB 256   // scan phase-1 blocks (requires n_nodes <= NB*256)
#define TP 128   // CSR positions per agg block (2 waves x 64)
#define CH 8     // Ps prefetch chunk

typedef __attribute__((ext_vector_type(8))) short bf16x8;
typedef __attribute__((ext_vector_type(4))) float f32x4;

__device__ inline unsigned pack_bf16(float a, float b) {
    unsigned ua = __float_as_uint(a), ub = __float_as_uint(b);
    ua = (ua + 0x7fffu + ((ua >> 16) & 1u)) >> 16;     // RNE bf16
    ub = (ub + 0x7fffu + ((ub >> 16) & 1u)) >> 16;
    return ua | (ub << 16);
}
__device__ inline unsigned short bf16_1(float a) {
    unsigned u = __float_as_uint(a);
    return (unsigned short)((u + 0x7fffu + ((u >> 16) & 1u)) >> 16);
}
__device__ inline float bf16f(unsigned short v) {
    return __uint_as_float((unsigned)v << 16);
}

union bfu { unsigned u[4]; bf16x8 v; };

// ---------------------------------------------------------------------------
// K1: MFMA per-node projections (bf16 tables) + degree histogram WITH RANK.
// ---------------------------------------------------------------------------
__global__ void __launch_bounds__(256) pre_hist_kernel(
    const float* __restrict__ node, const float* __restrict__ W_e,
    const int* __restrict__ dst,
    unsigned short* __restrict__ PsB, unsigned short* __restrict__ PdB,
    int* __restrict__ cnt, int* __restrict__ rank_,
    int n_nodes, int n_edges)
{
    const int t    = threadIdx.x;
    const int lane = t & 63;
    const int w    = __builtin_amdgcn_readfirstlane((int)(t >> 6));
    const int l15  = lane & 15;
    const int k0   = (lane >> 4) << 3;

    bfu bS[4][2], bD[4][2];
#pragma unroll
    for (int Nt = 0; Nt < 4; ++Nt) {
        const int col = (Nt << 4) | l15;
#pragma unroll
        for (int ks = 0; ks < 2; ++ks) {
            float ws[8], wd[8];
#pragma unroll
            for (int e = 0; e < 8; ++e) {
                ws[e] = W_e[(ks * 32 + k0 + e) * DO + col];
                wd[e] = W_e[(96 + ks * 32 + k0 + e) * DO + col];
            }
#pragma unroll
            for (int q = 0; q < 4; ++q) {
                bS[Nt][ks].u[q] = pack_bf16(ws[2 * q], ws[2 * q + 1]);
                bD[Nt][ks].u[q] = pack_bf16(wd[2 * q], wd[2 * q + 1]);
            }
        }
    }

    const int row0 = blockIdx.x * 64 + w * 16;
    if (row0 < n_nodes) {
        bfu aF[2];
#pragma unroll
        for (int ks = 0; ks < 2; ++ks) {
            const int r = min(row0 + l15, n_nodes - 1);
            const float* __restrict__ p = node + (size_t)r * DN + ks * 32 + k0;
            const float4 f0 = *(const float4*)p;
            const float4 f1 = *(const float4*)(p + 4);
            aF[ks].u[0] = pack_bf16(f0.x, f0.y);
            aF[ks].u[1] = pack_bf16(f0.z, f0.w);
            aF[ks].u[2] = pack_bf16(f1.x, f1.y);
            aF[ks].u[3] = pack_bf16(f1.z, f1.w);
        }
        const int rb = row0 + ((lane >> 4) << 2);
#pragma unroll
        for (int Nt = 0; Nt < 4; ++Nt) {
            const f32x4 z = {0.f, 0.f, 0.f, 0.f};
            f32x4 aS = __builtin_amdgcn_mfma_f32_16x16x32_bf16(aF[0].v, bS[Nt][0].v, z, 0, 0, 0);
            aS = __builtin_amdgcn_mfma_f32_16x16x32_bf16(aF[1].v, bS[Nt][1].v, aS, 0, 0, 0);
            f32x4 aD = __builtin_amdgcn_mfma_f32_16x16x32_bf16(aF[0].v, bD[Nt][0].v, z, 0, 0, 0);
            aD = __builtin_amdgcn_mfma_f32_16x16x32_bf16(aF[1].v, bD[Nt][1].v, aD, 0, 0, 0);
            const int col = (Nt << 4) | l15;
#pragma unroll
            for (int r = 0; r < 4; ++r) {
                if (rb + r < n_nodes) {
                    PsB[(size_t)(rb + r) * DO + col] = bf16_1(aS[r]);
                    PdB[(size_t)(rb + r) * DO + col] = bf16_1(aD[r]);
                }
            }
        }
    }

    const int gt = blockIdx.x * blockDim.x + t;
    const int nt = gridDim.x * blockDim.x;
    for (int e = gt; e < n_edges; e += nt)
        rank_[e] = atomicAdd(&cnt[dst[e]], 1);
}

// ---------------------------------------------------------------------------
// K2: per-block local exclusive scan + block sums; also zeroes msum.
// ---------------------------------------------------------------------------
__global__ void __launch_bounds__(256) scan_partial(
    const int* __restrict__ cnt, int* __restrict__ local,
    int* __restrict__ bsum, float* __restrict__ msum, int n_nodes)
{
    const int C = (n_nodes + NB - 1) / NB;
    const int t = threadIdx.x, lane = t & 63, w = t >> 6;
    const int i = blockIdx.x * C + t;

    int v = (t < C && i < n_nodes) ? cnt[i] : 0;
    int incl = v;
#pragma unroll
    for (int off = 1; off < 64; off <<= 1) {
        int u = __shfl_up(incl, off, 64);
        if (lane >= off) incl += u;
    }
    __shared__ int ws[4], wo[4];
    if (lane == 63) ws[w] = incl;
    __syncthreads();
    if (t == 0) {
        int r = 0;
#pragma unroll
        for (int q = 0; q < 4; ++q) { wo[q] = r; r += ws[q]; }
        bsum[blockIdx.x] = r;
    }
    __syncthreads();
    if (t < C && i < n_nodes) local[i] = incl - v + wo[w];

    const size_t nf4 = (size_t)n_nodes * DO / 4;
    float4* __restrict__ m4 = (float4*)msum;
    const size_t g0 = (size_t)blockIdx.x * blockDim.x + t;
    const size_t gs = (size_t)gridDim.x * blockDim.x;
    const float4 z4 = make_float4(0.f, 0.f, 0.f, 0.f);
    for (size_t j = g0; j < nf4; j += gs) m4[j] = z4;
}

// ---------------------------------------------------------------------------
// K3: merged scan_final + scatter (atomic-free via rank).
// ---------------------------------------------------------------------------
__global__ void __launch_bounds__(256) scatter_scan_kernel(
    const int* __restrict__ dst, const int* __restrict__ src,
    const int* __restrict__ rank_, const int* __restrict__ local,
    const int* __restrict__ bsum,
    int* __restrict__ row_start, int2* __restrict__ csr,
    int n_nodes, int n_edges, int C)
{
    __shared__ int boff[NB];
    const int t = threadIdx.x, lane = t & 63, w = t >> 6;

    {   // redundant per-block exclusive scan of bsum[0..NB)
        int v = bsum[t];
        int incl = v;
#pragma unroll
        for (int off = 1; off < 64; off <<= 1) {
            int u = __shfl_up(incl, off, 64);
            if (lane >= off) incl += u;
        }
        __shared__ int ws[4], wo[4];
        if (lane == 63) ws[w] = incl;
        __syncthreads();
        if (t == 0) {
            int r = 0;
#pragma unroll
            for (int q = 0; q < 4; ++q) { wo[q] = r; r += ws[q]; }
        }
        __syncthreads();
        boff[t] = incl - v + wo[w];
    }
    __syncthreads();

    if (blockIdx.x < NB) {      // materialize row_start
        const int i = blockIdx.x * C + t;
        if (t < C && i < n_nodes) row_start[i] = local[i] + boff[blockIdx.x];
        if (blockIdx.x == 0 && t == 0) row_start[n_nodes] = n_edges;
    }

    const int e = blockIdx.x * blockDim.x + t;
    if (e < n_edges) {
        const int d = dst[e];
        const int p = local[d] + boff[(unsigned)d / (unsigned)C] + rank_[e];
        csr[p] = make_int2(e, src[e] | (d << 16));
    }
}

// ---------------------------------------------------------------------------
// K4: MFMA edge-message + segment aggregation — R15 full-buffer structure
// (proven 60.4 us; the R16 half-split regressed: fewer gathers in flight).
// ---------------------------------------------------------------------------
__global__ void __launch_bounds__(128) agg_mfma_kernel(
    const float* __restrict__ edge,
    const float* __restrict__ W_e, const float* __restrict__ b_e,
    const unsigned short* __restrict__ PsB, const unsigned short* __restrict__ PdB,
    const int* __restrict__ row_start, const int2* __restrict__ csr,
    float* __restrict__ msum, int n_edges)
{
    __shared__ unsigned lds_m[2][32][68];   // 17.4 KB: bf16-paired raw scores

    const int t    = threadIdx.x;
    const int lane = t & 63;
    const int wid  = __builtin_amdgcn_readfirstlane((int)(t >> 6));
    const int wbeg = blockIdx.x * TP + wid * 64;
    const int wcnt = min(n_edges - wbeg, 64);
    if (wcnt <= 0) return;

    const int l15 = lane & 15;
    const int k0  = (lane >> 4) << 3;

    bfu bfr[4];
#pragma unroll
    for (int Nt = 0; Nt < 4; ++Nt) {
        const int col = (Nt << 4) | l15;
        float wv[8];
#pragma unroll
        for (int e = 0; e < 8; ++e)
            wv[e] = W_e[(64 + k0 + e) * DO + col];
#pragma unroll
        for (int v2 = 0; v2 < 4; ++v2)
            bfr[Nt].u[v2] = pack_bf16(wv[2 * v2], wv[2 * v2 + 1]);
    }
    const float bj = b_e[lane];

    const int2 my2 = csr[min(wbeg + lane, n_edges - 1)];

#pragma unroll
    for (int Mt = 0; Mt < 4; ++Mt) {
        const int eA = __shfl(my2.x, (Mt << 4) | l15, 64);
        const float* __restrict__ ep = edge + (size_t)(unsigned)eA * DE + k0;
        const float4 f0 = *(const float4*)(ep);
        const float4 f1 = *(const float4*)(ep + 4);
        bfu afr;
        afr.u[0] = pack_bf16(f0.x, f0.y);
        afr.u[1] = pack_bf16(f0.z, f0.w);
        afr.u[2] = pack_bf16(f1.x, f1.y);
        afr.u[3] = pack_bf16(f1.z, f1.w);
        const int rp0 = (Mt << 3) + ((lane >> 4) << 1);
#pragma unroll
        for (int Nt = 0; Nt < 4; ++Nt) {
            f32x4 dz = {0.f, 0.f, 0.f, 0.f};
            f32x4 d = __builtin_amdgcn_mfma_f32_16x16x32_bf16(afr.v, bfr[Nt].v, dz, 0, 0, 0);
            const int col = (Nt << 4) | l15;
            lds_m[wid][rp0][col]     = pack_bf16(d[0], d[1]);
            lds_m[wid][rp0 + 1][col] = pack_bf16(d[2], d[3]);
        }
    }

    float acc = 0.f, bpd = 0.f;
    int cur_d = -1;

#define FLUSH()                                                         \
    {                                                                   \
        if (row_start[cur_d] >= wbeg)                                   \
            msum[(size_t)cur_d * DO + lane] = acc;                      \
        else                                                            \
            unsafeAtomicAdd(&msum[(size_t)cur_d * DO + lane], acc);     \
    }

#define ISSUE(CHK, BUF)                                                 \
    _Pragma("unroll")                                                   \
    for (int q = 0; q < CH; ++q) {                                      \
        const int y = __builtin_amdgcn_readlane(my2.y, (CHK) * CH + q); \
        BUF[q] = PsB[(size_t)(unsigned)(y & 0xffff) * DO + lane];       \
    }

#define CONSUME(CHK, BUF)                                               \
    {                                                                   \
        unsigned um[4];                                                 \
        _Pragma("unroll")                                               \
        for (int h = 0; h < 4; ++h)                                     \
            um[h] = lds_m[wid][(CHK) * 4 + h][lane];                    \
        _Pragma("unroll")                                               \
        for (int q = 0; q < CH; ++q) {                                  \
            const int y = __builtin_amdgcn_readlane(my2.y, (CHK) * CH + q); \
            const int d = (int)(((unsigned)y) >> 16);                   \
            if (d != cur_d) {                                           \
                if (cur_d >= 0) FLUSH();                                \
                acc = 0.f;                                              \
                cur_d = d;                                              \
                bpd = bj + bf16f(PdB[(size_t)(unsigned)d * DO + lane]); \
            }                                                           \
            const unsigned u = um[q >> 1];                              \
            const float mv = (q & 1) ? __uint_as_float(u & 0xffff0000u) \
                                     : __uint_as_float(u << 16);        \
            acc += fmaxf(mv + bpd + __uint_as_float((unsigned)BUF[q] << 16), 0.f); \
        }                                                               \
    }

    if (wcnt == 64) {
        unsigned short pnA[CH], pnB[CH], pnC[CH];
        ISSUE(0, pnA) ISSUE(1, pnB)
        ISSUE(2, pnC) CONSUME(0, pnA)
        ISSUE(3, pnA) CONSUME(1, pnB)
        ISSUE(4, pnB) CONSUME(2, pnC)
        ISSUE(5, pnC) CONSUME(3, pnA)
        ISSUE(6, pnA) CONSUME(4, pnB)
        ISSUE(7, pnB) CONSUME(5, pnC)
        CONSUME(6, pnA)
        CONSUME(7, pnB)
    } else {
        for (int p = 0; p < wcnt; ++p) {
            const int y = __builtin_amdgcn_readlane(my2.y, p);
            const int s = y & 0xffff;
            const int d = (int)(((unsigned)y) >> 16);
            const float ps = bf16f(PsB[(size_t)(unsigned)s * DO + lane]);
            if (d != cur_d) {
                if (cur_d >= 0) FLUSH();
                acc = 0.f;
                cur_d = d;
                bpd = bj + bf16f(PdB[(size_t)(unsigned)d * DO + lane]);
            }
            const unsigned u = lds_m[wid][p >> 1][lane];
            const float mv = (p & 1) ? __uint_as_float(u & 0xffff0000u)
                                     : __uint_as_float(u << 16);
            acc += fmaxf(mv + bpd + ps, 0.f);
        }
    }

    {   // final flush
        const int sb = row_start[cur_d];
        const int se = row_start[cur_d + 1];
        if (sb >= wbeg && se <= wbeg + wcnt)
            msum[(size_t)cur_d * DO + lane] = acc;
        else
            unsafeAtomicAdd(&msum[(size_t)cur_d * DO + lane], acc);
    }
#undef FLUSH
#undef ISSUE
#undef CONSUME
}

// ---------------------------------------------------------------------------
// K5: MFMA node update: out = relu((msum@Wt)/deg + node@Wb + b_v).
// ---------------------------------------------------------------------------
__global__ void __launch_bounds__(256) node_out_kernel(
    const float* __restrict__ node, const float* __restrict__ msum,
    const int* __restrict__ row_start,
    const float* __restrict__ W_v, const float* __restrict__ b_v,
    float* __restrict__ out, int n_nodes)
{
    const int t    = threadIdx.x;
    const int lane = t & 63;
    const int w    = __builtin_amdgcn_readfirstlane((int)(t >> 6));
    const int l15  = lane & 15;
    const int k0   = (lane >> 4) << 3;

    bfu bT[4][2], bB[4][2];
    float bv[4];
#pragma unroll
    for (int Nt = 0; Nt < 4; ++Nt) {
        const int col = (Nt << 4) | l15;
        bv[Nt] = b_v[col];
#pragma unroll
        for (int ks = 0; ks < 2; ++ks) {
            float wt[8], wb[8];
#pragma unroll
            for (int e = 0; e < 8; ++e) {
                wt[e] = W_v[(ks * 32 + k0 + e) * DO + col];
                wb[e] = W_v[(64 + ks * 32 + k0 + e) * DO + col];
            }
#pragma unroll
            for (int q = 0; q < 4; ++q) {
                bT[Nt][ks].u[q] = pack_bf16(wt[2 * q], wt[2 * q + 1]);
                bB[Nt][ks].u[q] = pack_bf16(wb[2 * q], wb[2 * q + 1]);
            }
        }
    }

    const int row0 = blockIdx.x * 64 + w * 16;
    if (row0 >= n_nodes) return;

    bfu aM[2], aN[2];
#pragma unroll
    for (int ks = 0; ks < 2; ++ks) {
        const int r = min(row0 + l15, n_nodes - 1);
        const float* __restrict__ pm = msum + (size_t)r * DO + ks * 32 + k0;
        const float* __restrict__ pn = node + (size_t)r * DN + ks * 32 + k0;
        const float4 m0 = *(const float4*)pm;
        const float4 m1 = *(const float4*)(pm + 4);
        const float4 n0 = *(const float4*)pn;
        const float4 n1 = *(const float4*)(pn + 4);
        aM[ks].u[0] = pack_bf16(m0.x, m0.y);
        aM[ks].u[1] = pack_bf16(m0.z, m0.w);
        aM[ks].u[2] = pack_bf16(m1.x, m1.y);
        aM[ks].u[3] = pack_bf16(m1.z, m1.w);
        aN[ks].u[0] = pack_bf16(n0.x, n0.y);
        aN[ks].u[1] = pack_bf16(n0.z, n0.w);
        aN[ks].u[2] = pack_bf16(n1.x, n1.y);
        aN[ks].u[3] = pack_bf16(n1.z, n1.w);
    }

    f32x4 accT[4], accB[4];
#pragma unroll
    for (int Nt = 0; Nt < 4; ++Nt) {
        const f32x4 z = {0.f, 0.f, 0.f, 0.f};
        f32x4 aT = __builtin_amdgcn_mfma_f32_16x16x32_bf16(aM[0].v, bT[Nt][0].v, z, 0, 0, 0);
        aT = __builtin_amdgcn_mfma_f32_16x16x32_bf16(aM[1].v, bT[Nt][1].v, aT, 0, 0, 0);
        f32x4 aB = __builtin_amdgcn_mfma_f32_16x16x32_bf16(aN[0].v, bB[Nt][0].v, z, 0, 0, 0);
        aB = __builtin_amdgcn_mfma_f32_16x16x32_bf16(aN[1].v, bB[Nt][1].v, aB, 0, 0, 0);
        accT[Nt] = aT;
        accB[Nt] = aB;
    }

    const int rb = row0 + ((lane >> 4) << 2);
#pragma unroll
    for (int r = 0; r < 4; ++r) {
        const int row = rb + r;
        if (row < n_nodes) {
            const float dg = (float)(row_start[row + 1] - row_start[row]);
            const float inv = (dg > 0.f) ? 1.f / dg : 0.f;
#pragma unroll
            for (int Nt = 0; Nt < 4; ++Nt) {
                const int col = (Nt << 4) | l15;
                const float val = accT[Nt][r] * inv + accB[Nt][r] + bv[Nt];
                out[(size_t)row * DO + col] = fmaxf(val, 0.f);
            }
        }
    }
}

extern "C" void kernel_launch(void* const* d_in, const int* in_sizes, int n_in,
                              void* d_out, int out_size, void* d_ws, size_t ws_size,
                              hipStream_t stream)
{
    const float* node = (const float*)d_in[0];
    const float* edge = (const float*)d_in[1];
    const int*   src  = (const int*)d_in[2];
    const int*   dst  = (const int*)d_in[3];
    const float* W_e  = (const float*)d_in[4];
    const float* b_e  = (const float*)d_in[5];
    const float* W_v  = (const float*)d_in[6];
    const float* b_v  = (const float*)d_in[7];
    float* out = (float*)d_out;

    const int n_nodes = in_sizes[0] / DN;
    const int n_edges = in_sizes[2];
    const int ntiles  = (n_nodes + 63) / 64;
    const int C       = (n_nodes + NB - 1) / NB;

    // Workspace: PsB | PdB (bf16) | msum | cnt | row_start | local | bsum |
    //            rank | csr(int2)
    unsigned short* PsB = (unsigned short*)d_ws;
    unsigned short* PdB = PsB + (size_t)n_nodes * DO;
    float* msum = (float*)(PdB + (size_t)n_nodes * DO);
    int* cnt       = (int*)(msum + (size_t)n_nodes * DO);
    int* row_start = cnt + n_nodes;
    int* local     = row_start + (n_nodes + 1);
    int* bsum      = local + n_nodes;
    int* rank_     = bsum + NB;
    int2* csr      = (int2*)(((size_t)(rank_ + n_edges) + 15) & ~(size_t)15);

    hipMemsetAsync(cnt, 0, (size_t)n_nodes * sizeof(int), stream);

    pre_hist_kernel<<<ntiles, 256, 0, stream>>>(node, W_e, dst, PsB, PdB,
                                                cnt, rank_, n_nodes, n_edges);
    scan_partial<<<NB, 256, 0, stream>>>(cnt, local, bsum, msum, n_nodes);
    scatter_scan_kernel<<<(n_edges + 255) / 256, 256, 0, stream>>>(
        dst, src, rank_, local, bsum, row_start, csr, n_nodes, n_edges, C);
    agg_mfma_kernel<<<(n_edges + TP - 1) / TP, 128, 0, stream>>>(edge, W_e, b_e, PsB, PdB,
                                                                 row_start, csr, msum, n_edges);
    node_out_kernel<<<ntiles, 256, 0, stream>>>(node, msum, row_start, W_v, b_v,
                                                out, n_nodes);
}